// Round 2
// baseline (714.594 us; speedup 1.0000x reference)
//
#include <hip/hip_runtime.h>
#include <hip/hip_bf16.h>

#define EMBED 300
#define HD    128
#define LLEN  512
#define G4    512   // 4*H

// Workspace layout (floats):
// pre_g: [2][4][512][512]  off 0        size 2097152
// lstm : [2][4][512][128]  off 2097152  size 524288
// proj : [2][4][512][128]  off 2621440  size 524288
// mx   : [2][4][128]       off 3145728  size 1024
// feat : [2][4][128]       off 3146752  size 1024
#define OFF_LSTM 2097152
#define OFF_PROJ 2621440
#define OFF_MX   3145728
#define OFF_FEAT 3146752

// ---------------- K1: embedding gather + X @ W_ih + b  → pre_g ----------------
// M = 2*4*512 = 4096 rows, K = 300, N = 512. Tile 64x64, Kc=32, 256 threads.
__global__ __launch_bounds__(256) void k1_gemm(
    const int* __restrict__ qc, const int* __restrict__ ac,
    const float* __restrict__ emb, const float* __restrict__ wih,
    const float* __restrict__ bl, float* __restrict__ preg)
{
    __shared__ float As[32][65];   // [kk][m], padded (transposed store)
    __shared__ float Bs[32][64];   // [kk][n]
    const int m0 = blockIdx.x * 64;
    const int n0 = blockIdx.y * 64;
    const int tid = threadIdx.x;
    const int tx = tid & 15, ty = tid >> 4;
    float acc[4][4] = {};

    for (int k0 = 0; k0 < 300; k0 += 32) {
        // A tile: 64 rows x 32 k  (gather through embedding)
        #pragma unroll
        for (int i = 0; i < 8; ++i) {
            int e = tid + i * 256;
            int m = e >> 5, kk = e & 31;
            int row = m0 + m;
            int c = row >> 11, b = (row >> 9) & 3, t = row & 511;
            int tok = (c == 0 ? qc : ac)[b * LLEN + t];
            int k = k0 + kk;
            As[kk][m] = (k < 300) ? emb[(size_t)tok * EMBED + k] : 0.f;
        }
        // B tile: 32 k x 64 n
        #pragma unroll
        for (int i = 0; i < 8; ++i) {
            int e = tid + i * 256;
            int kk = e >> 6, n = e & 63;
            int k = k0 + kk;
            Bs[kk][n] = (k < 300) ? wih[k * G4 + n0 + n] : 0.f;
        }
        __syncthreads();
        #pragma unroll
        for (int kk = 0; kk < 32; ++kk) {
            float a[4], bv[4];
            #pragma unroll
            for (int i = 0; i < 4; ++i) a[i] = As[kk][ty * 4 + i];
            #pragma unroll
            for (int j = 0; j < 4; ++j) bv[j] = Bs[kk][tx * 4 + j];
            #pragma unroll
            for (int i = 0; i < 4; ++i)
                #pragma unroll
                for (int j = 0; j < 4; ++j)
                    acc[i][j] += a[i] * bv[j];
        }
        __syncthreads();
    }
    #pragma unroll
    for (int i = 0; i < 4; ++i) {
        int row = m0 + ty * 4 + i;
        #pragma unroll
        for (int j = 0; j < 4; ++j) {
            int n = n0 + tx * 4 + j;
            preg[(size_t)row * G4 + n] = acc[i][j] + bl[n];
        }
    }
}

// ---------------- K2: recurrent LSTM scan. 8 WGs (one per sequence) ----------------
__global__ __launch_bounds__(512, 1) void k2_lstm(
    const float* __restrict__ whh, const float* __restrict__ preg,
    float* __restrict__ lstm)
{
    const int cb = blockIdx.x;          // c*4 + b
    const int j = threadIdx.x;          // gate column 0..511
    const float* pg = preg + (size_t)cb * LLEN * G4;
    float* out = lstm + (size_t)cb * LLEN * HD;

    float w[128];
    #pragma unroll
    for (int k = 0; k < 128; ++k) w[k] = whh[k * G4 + j];

    __shared__ __align__(16) float hbuf[128];
    __shared__ float gbuf[512];
    if (j < 128) hbuf[j] = 0.f;
    float cst = 0.f;
    __syncthreads();

    const int sec = j >> 7;             // 0:i 1:f 2:g 3:o
    float pgv = pg[j];
    for (int t = 0; t < LLEN; ++t) {
        float nxt = (t < LLEN - 1) ? pg[(size_t)(t + 1) * G4 + j] : 0.f;
        float acc = pgv;
        const float4* h4 = (const float4*)hbuf;
        #pragma unroll
        for (int k4 = 0; k4 < 32; ++k4) {
            float4 hv = h4[k4];
            acc += hv.x * w[4 * k4 + 0];
            acc += hv.y * w[4 * k4 + 1];
            acc += hv.z * w[4 * k4 + 2];
            acc += hv.w * w[4 * k4 + 3];
        }
        float v;
        if (sec == 2) v = tanhf(acc);
        else          v = 1.f / (1.f + __expf(-acc));
        gbuf[j] = v;
        __syncthreads();
        if (j < 128) {
            float iv = gbuf[j], fv = gbuf[128 + j], gv = gbuf[256 + j], ov = gbuf[384 + j];
            cst = fv * cst + iv * gv;
            float h = ov * tanhf(cst);
            hbuf[j] = h;
            out[(size_t)t * HD + j] = h;
        }
        __syncthreads();
        pgv = nxt;
    }
}

// ---------------- K3: proj = lstm @ Wa_part (per side). 64 WGs ----------------
__global__ __launch_bounds__(512) void k3_proj(
    const float* __restrict__ wa, const float* __restrict__ lstm,
    float* __restrict__ proj)
{
    const int idx = blockIdx.x;             // 0..63
    const int tc = idx & 7, b = (idx >> 3) & 3, s = idx >> 5;
    __shared__ float wsm[128][128];
    const int tid = threadIdx.x;
    #pragma unroll
    for (int i = 0; i < 32; ++i) {
        int e = tid + i * 512;
        int k = e >> 7, h = e & 127;
        wsm[k][h] = wa[(s * 128 + k) * 128 + h];
    }
    __syncthreads();
    const float* lb = lstm + ((size_t)(s * 4 + b)) * LLEN * HD;
    float* pb = proj + ((size_t)(s * 4 + b)) * LLEN * HD;
    const int h = tid & 127, ts = tid >> 7;
    for (int i = 0; i < 16; ++i) {
        int t = tc * 64 + i * 4 + ts;
        const float* lr = lb + (size_t)t * HD;
        float acc = 0.f;
        #pragma unroll
        for (int k = 0; k < 128; ++k) acc += lr[k] * wsm[k][h];
        pb[(size_t)t * HD + h] = acc;
    }
}

// ---------------- K3b: per-(side,b,h) max over t ----------------
__global__ void k3_max(const float* __restrict__ proj, float* __restrict__ mx)
{
    const int cb = blockIdx.x;   // 0..7
    const int h = threadIdx.x;   // 0..127
    const float* p = proj + (size_t)cb * LLEN * HD;
    float m = -1e30f;
    #pragma unroll 8
    for (int t = 0; t < LLEN; ++t) m = fmaxf(m, p[(size_t)t * HD + h]);
    mx[cb * HD + h] = m;
}

// ---------------- K4: r (on the fly) + scores + softmax + feature ----------------
__global__ __launch_bounds__(512) void k4_attn(
    const float* __restrict__ lstm, const float* __restrict__ proj,
    const float* __restrict__ mx, const float* __restrict__ ba,
    const float* __restrict__ wq, const float* __restrict__ bq,
    const float* __restrict__ wans, const float* __restrict__ bans,
    float* __restrict__ feat)
{
    const int blk = blockIdx.x;          // s*4 + b
    const int s = blk >> 2, b = blk & 3;
    const float* wv = (s == 0) ? wq : wans;
    const float bias = (s == 0) ? bq[0] : bans[0];
    const float* lb = lstm + ((size_t)(s * 4 + b)) * LLEN * HD;       // own lstm
    const float* po = proj + ((size_t)((1 - s) * 4 + b)) * LLEN * HD; // other proj
    __shared__ float sl[512];
    __shared__ float red[512];
    __shared__ float bcast[2];
    const int tid = threadIdx.x;
    const int wave = tid >> 6, lane = tid & 63;

    const float mb1 = mx[(s * 4 + b) * HD + lane] + ba[lane];
    const float mb2 = mx[(s * 4 + b) * HD + lane + 64] + ba[lane + 64];
    const float wv1a = wv[lane], wv1b = wv[lane + 64];
    const float wv2a = wv[128 + lane], wv2b = wv[192 + lane];

    for (int jj = 0; jj < 64; ++jj) {
        int j = wave + jj * 8;
        float p1 = po[(size_t)j * HD + lane], p2 = po[(size_t)j * HD + lane + 64];
        float r1 = tanhf(mb1 + p1), r2 = tanhf(mb2 + p2);
        float sc = lb[(size_t)j * HD + lane] * wv1a + lb[(size_t)j * HD + lane + 64] * wv1b
                 + r1 * wv2a + r2 * wv2b;
        #pragma unroll
        for (int o = 32; o; o >>= 1) sc += __shfl_down(sc, o, 64);
        if (lane == 0) sl[j] = sc + bias;
    }
    __syncthreads();

    // stable softmax over 512 scores
    float v = sl[tid];
    float m = v;
    #pragma unroll
    for (int o = 32; o; o >>= 1) m = fmaxf(m, __shfl_xor(m, o, 64));
    if (lane == 0) red[wave] = m;
    __syncthreads();
    if (tid == 0) { float mm = red[0]; for (int i = 1; i < 8; ++i) mm = fmaxf(mm, red[i]); bcast[0] = mm; }
    __syncthreads();
    float e = __expf(v - bcast[0]);
    float ssum = e;
    #pragma unroll
    for (int o = 32; o; o >>= 1) ssum += __shfl_xor(ssum, o, 64);
    if (lane == 0) red[wave] = ssum;
    __syncthreads();
    if (tid == 0) { float t = 0.f; for (int i = 0; i < 8; ++i) t += red[i]; bcast[1] = t; }
    __syncthreads();
    sl[tid] = e / bcast[1];              // alpha
    __syncthreads();

    // feature = sum_j alpha_j * r_j
    const int h = tid & 127, q4 = tid >> 7;
    const float mbh = mx[(s * 4 + b) * HD + h] + ba[h];
    float acc = 0.f;
    for (int jj = 0; jj < 128; ++jj) {
        int j = q4 + jj * 4;
        float r = tanhf(mbh + po[(size_t)j * HD + h]);
        acc += sl[j] * r;
    }
    red[tid] = acc;
    __syncthreads();
    if (tid < 128)
        feat[(s * 4 + b) * HD + tid] = red[tid] + red[128 + tid] + red[256 + tid] + red[384 + tid];
}

// ---------------- K5: final classifier + log_softmax + argmax (fp32 out) ----------------
__global__ void k5_final(const float* __restrict__ feat,
                         const float* __restrict__ wlast, const float* __restrict__ blast,
                         float* __restrict__ outp)
{
    const int tid = threadIdx.x;
    if (tid < 4) {
        const int b = tid;
        float l0 = blast[0], l1 = blast[1];
        for (int k = 0; k < 256; ++k) {
            float f = (k < 128) ? feat[b * HD + k] : feat[(4 + b) * HD + (k - 128)];
            l0 += f * wlast[k * 2 + 0];
            l1 += f * wlast[k * 2 + 1];
        }
        float mxl = fmaxf(l0, l1);
        float lse = mxl + logf(__expf(l0 - mxl) + __expf(l1 - mxl));
        // d_out is float* (reference outputs are f32 score + int predict)
        outp[b * 2 + 0] = l0 - lse;
        outp[b * 2 + 1] = l1 - lse;
        outp[8 + b]     = (l1 > l0) ? 1.f : 0.f;
    }
}

extern "C" void kernel_launch(void* const* d_in, const int* in_sizes, int n_in,
                              void* d_out, int out_size, void* d_ws, size_t ws_size,
                              hipStream_t stream)
{
    const int*   qc    = (const int*)d_in[0];
    const int*   ac    = (const int*)d_in[1];
    const float* emb   = (const float*)d_in[2];
    const float* wih   = (const float*)d_in[3];
    const float* whh   = (const float*)d_in[4];
    const float* bl    = (const float*)d_in[5];
    const float* wa    = (const float*)d_in[6];
    const float* ba    = (const float*)d_in[7];
    const float* wq    = (const float*)d_in[8];
    const float* bq    = (const float*)d_in[9];
    const float* wans  = (const float*)d_in[10];
    const float* bans  = (const float*)d_in[11];
    const float* wlast = (const float*)d_in[12];
    const float* blast = (const float*)d_in[13];

    float* ws   = (float*)d_ws;
    float* preg = ws;
    float* lstm = ws + OFF_LSTM;
    float* proj = ws + OFF_PROJ;
    float* mx   = ws + OFF_MX;
    float* feat = ws + OFF_FEAT;

    k1_gemm<<<dim3(64, 8), 256, 0, stream>>>(qc, ac, emb, wih, bl, preg);
    k2_lstm<<<8, 512, 0, stream>>>(whh, preg, lstm);
    k3_proj<<<64, 512, 0, stream>>>(wa, lstm, proj);
    k3_max<<<8, 128, 0, stream>>>(proj, mx);
    k4_attn<<<8, 512, 0, stream>>>(lstm, proj, mx, ba, wq, bq, wans, bans, feat);
    k5_final<<<1, 64, 0, stream>>>(feat, wlast, blast, (float*)d_out);
}